// Round 8
// baseline (25.085 us; speedup 1.0000x reference)
//
#include <hip/hip_runtime.h>

constexpr int    NN      = 8192;
constexpr float  MARGIN  = 0.01f;
constexpr int    BT      = 256;            // threads per block
constexpr int    FI      = 4;              // i-rows per thread
constexpr int    TI      = BT * FI;        // 1024 i-rows per block
constexpr int    TJ      = 64;             // j-chunk per block
constexpr int    NTI     = NN / TI;        // 8
constexpr int    NTJ     = NN / TJ;        // 128
constexpr int    CPR     = TI / TJ;        // 16 j-chunks per diagonal block
constexpr int    NBLOCKS = NTI * NTJ - CPR * (NTI * (NTI - 1) / 2); // 576

// d_ws layout: [0] u32 counter (memset 0 each call); [64] f32 price_part[8];
//              [256] f32 rank_part[576]
//
// Symmetry: hinge(i,j)==hinge(j,i). For i-tile ib, chunks t<CPR lie inside the
// 1024x1024 diagonal tile -> ordered pairs once, no doubling; t>=CPR ->
// strictly upper tiles, doubled. i==j slots contribute exactly MARGIN each
// (bitwise-identical r on both paths -> pd=0); subtracted analytically.
// count = NN*(NN-1) (continuous data, no off-diag ties; absmax==0 rounds 3-7).
__global__ __launch_bounds__(BT)
void pair_kernel(const float* __restrict__ pred,
                 const float* __restrict__ act,
                 const float* __restrict__ prev,
                 unsigned int* __restrict__ counter,
                 float* __restrict__ rank_part,
                 float* __restrict__ price_part,
                 float* __restrict__ out)
{
    // decode flat block id -> (ib, t); row ib has (NTJ - CPR*ib) j-chunks
    int t  = blockIdx.x;
    int ib = 0;
    while (t >= NTJ - CPR * ib) { t -= NTJ - CPR * ib; ++ib; }
    const int  jc        = CPR * ib + t;
    const bool diag_like = (t < CPR);
    const bool do_price  = (t == 0);

    __shared__ alignas(16) float2 s_t[TJ];

    const int tid = threadIdx.x;
    if (tid < TJ) {
        const int   j   = jc * TJ + tid;
        const float pv  = prev[j];
        const float rcp = __builtin_amdgcn_rcpf(pv);
        s_t[tid] = make_float2((pred[j] - pv) * rcp, (act[j] - pv) * rcp);
    }

    // 4 i-rows per thread: ib*1024 + tid + {0,256,512,768} (coalesced)
    float pri[FI], ari[FI];
    float pp = 0.f;
#pragma unroll
    for (int f = 0; f < FI; ++f) {
        const int   i   = ib * TI + f * BT + tid;
        const float pv  = prev[i];
        const float p   = pred[i];
        const float a   = act[i];
        const float rcp = __builtin_amdgcn_rcpf(pv);
        pri[f] = (p - pv) * rcp;
        ari[f] = (a - pv) * rcp;
        if (do_price) {
            const float d = p - a;
            pp += d * d;
        }
    }

    __syncthreads();

    float acc[FI] = {0.f, 0.f, 0.f, 0.f};

#define PAIR(f, pj, aj)                                     \
    {                                                       \
        const float ad = ari[f] - (aj);                     \
        const float pd = pri[f] - (pj);                     \
        const float s  = (ad > 0.0f) ? -1.0f : 1.0f;        \
        acc[f] += fmaxf(0.0f, fmaf(s, pd, MARGIN));         \
    }

    const float4* __restrict__ s4 = (const float4*)s_t;   // 32 x (2 j's)
#pragma unroll
    for (int g = 0; g < TJ / 2; ++g) {
        const float4 q = s4[g];
        PAIR(0, q.x, q.y); PAIR(1, q.x, q.y);
        PAIR(2, q.x, q.y); PAIR(3, q.x, q.y);
        PAIR(0, q.z, q.w); PAIR(1, q.z, q.w);
        PAIR(2, q.z, q.w); PAIR(3, q.z, q.w);
    }
#undef PAIR

    float w = (acc[0] + acc[1]) + (acc[2] + acc[3]);
    if (!diag_like) w += w;                 // doubled tiles (exact in f32)

    // wave reduce f32, then LDS across the 4 waves
    for (int off = 32; off > 0; off >>= 1) w += __shfl_down(w, off, 64);
    __shared__ float r_s[4], r_p[4];
    __shared__ bool  lastf;
    if ((tid & 63) == 0) r_s[tid >> 6] = w;
    if (do_price) {
        for (int off = 32; off > 0; off >>= 1) pp += __shfl_down(pp, off, 64);
        if ((tid & 63) == 0) r_p[tid >> 6] = pp;
    }
    __syncthreads();

    if (tid == 0) {
        rank_part[blockIdx.x] = r_s[0] + r_s[1] + r_s[2] + r_s[3];
        if (do_price) price_part[ib] = r_p[0] + r_p[1] + r_p[2] + r_p[3];
        const unsigned tk = __hip_atomic_fetch_add(counter, 1u, __ATOMIC_ACQ_REL,
                                                   __HIP_MEMORY_SCOPE_AGENT);
        lastf = (tk == (unsigned)(NBLOCKS - 1));
    }
    __syncthreads();
    if (!lastf) return;

    // winner: final reduction (acquire on counter ordered all prior writes)
    double s = 0.0, p = 0.0;
    for (int k = tid; k < NBLOCKS; k += BT) s += (double)rank_part[k];
    if (tid < NTI) p = (double)price_part[tid];
    for (int off = 32; off > 0; off >>= 1) {
        s += __shfl_down(s, off, 64);
        p += __shfl_down(p, off, 64);
    }
    __shared__ double rs2[4], rp2[4];
    if ((tid & 63) == 0) { rs2[tid >> 6] = s; rp2[tid >> 6] = p; }
    __syncthreads();
    if (tid == 0) {
        const double S = rs2[0] + rs2[1] + rs2[2] + rs2[3];
        const double P = rp2[0] + rp2[1] + rp2[2] + rp2[3];
        const double rank = (S - (double)NN * (double)MARGIN)
                          / ((double)NN * (double)(NN - 1));
        out[0] = (float)(0.5 * (P / (double)NN) + 0.5 * rank);
    }
}

extern "C" void kernel_launch(void* const* d_in, const int* in_sizes, int n_in,
                              void* d_out, int out_size, void* d_ws, size_t ws_size,
                              hipStream_t stream)
{
    const float* pred = (const float*)d_in[0];
    const float* act  = (const float*)d_in[1];
    const float* prev = (const float*)d_in[2];

    char* w = (char*)d_ws;
    unsigned int* counter    = (unsigned int*)(w + 0);
    float*        price_part = (float*)(w + 64);
    float*        rank_part  = (float*)(w + 256);

    hipMemsetAsync(counter, 0, 4, stream);
    pair_kernel<<<NBLOCKS, BT, 0, stream>>>(pred, act, prev, counter,
                                            rank_part, price_part, (float*)d_out);
}

// Round 9
// 14.055 us; speedup vs baseline: 1.7847x; 1.7847x over previous
//
#include <hip/hip_runtime.h>

constexpr int    NN      = 8192;
constexpr float  MARGIN  = 0.01f;
constexpr int    BT      = 256;            // threads per block
constexpr int    FI      = 4;              // i-rows per thread
constexpr int    TI      = BT * FI;        // 1024 i-rows per block
constexpr int    TJ      = 32;             // j-chunk per block
constexpr int    NTI     = NN / TI;        // 8
constexpr int    NTJ     = NN / TJ;        // 256
constexpr int    CPR     = TI / TJ;        // 32 chunks per diagonal tile
constexpr int    NBLOCKS = NTI * NTJ - CPR * (NTI * (NTI - 1) / 2); // 1152

// Symmetry: hinge(i,j)==hinge(j,i). For i-tile ib, chunks t<CPR lie inside the
// 1024x1024 diagonal tile -> each ordered pair once, no doubling; t>=CPR ->
// strictly upper tiles, doubled. i==j slots contribute exactly MARGIN each
// (x-x=+0 -> mask=0 -> u=+0 -> h=MARGIN); subtracted analytically in finalize.
// count = NN*(NN-1) (continuous data, no off-diag ties; absmax==0 rounds 3-8).
__global__ __launch_bounds__(BT)
void pair_kernel(const float* __restrict__ pred,
                 const float* __restrict__ act,
                 const float* __restrict__ prev,
                 float* __restrict__ rank_part,    // [NBLOCKS]
                 float* __restrict__ price_part)   // [NTI]
{
    // decode flat block id -> (ib, t); row ib has (NTJ - CPR*ib) j-chunks
    int t  = blockIdx.x;
    int ib = 0;
    while (t >= NTJ - CPR * ib) { t -= NTJ - CPR * ib; ++ib; }
    const int  jc        = CPR * ib + t;
    const bool diag_like = (t < CPR);
    const bool do_price  = (t == 0);

    __shared__ alignas(16) float2 s_t[TJ];

    const int tid = threadIdx.x;
    if (tid < TJ) {
        const int   j   = jc * TJ + tid;
        const float pv  = prev[j];
        const float rcp = __builtin_amdgcn_rcpf(pv);
        s_t[tid] = make_float2((pred[j] - pv) * rcp, (act[j] - pv) * rcp);
    }

    // 4 i-rows per thread: ib*1024 + tid + {0,256,512,768} (coalesced)
    float pri[FI], ari[FI];
    float pp = 0.f;
#pragma unroll
    for (int f = 0; f < FI; ++f) {
        const int   i   = ib * TI + f * BT + tid;
        const float pv  = prev[i];
        const float p   = pred[i];
        const float a   = act[i];
        const float rcp = __builtin_amdgcn_rcpf(pv);
        pri[f] = (p - pv) * rcp;
        ari[f] = (a - pv) * rcp;
        if (do_price) {
            const float d = p - a;
            pp += d * d;
        }
    }

    __syncthreads();

    // hoist the whole j-tile into registers: 16 x ds_read_b128, one wait,
    // then the 128-PAIR loop is pure straight-line VALU (no memory ops).
    float4 q[TJ / 2];
    const float4* __restrict__ s4 = (const float4*)s_t;
#pragma unroll
    for (int g = 0; g < TJ / 2; ++g) q[g] = s4[g];

    float acc[FI] = {0.f, 0.f, 0.f, 0.f};

#define PAIR(f, pj, aj)                                             \
    {                                                               \
        const float    nad = (aj) - ari[f];       /* = -act_diff */ \
        const float    pd  = pri[f] - (pj);                         \
        const unsigned m   = __float_as_uint(nad) & 0x80000000u;    \
        const float    u   = __uint_as_float(__float_as_uint(pd) ^ m); \
        acc[f] += fmaxf(0.0f, u + MARGIN);                          \
    }

#pragma unroll
    for (int g = 0; g < TJ / 2; ++g) {
#pragma unroll
        for (int f = 0; f < FI; ++f) {
            PAIR(f, q[g].x, q[g].y);
            PAIR(f, q[g].z, q[g].w);
        }
    }
#undef PAIR

    float w = (acc[0] + acc[1]) + (acc[2] + acc[3]);
    if (!diag_like) w += w;                 // doubled tiles (exact in f32)

    for (int off = 32; off > 0; off >>= 1) w += __shfl_down(w, off, 64);
    __shared__ float r_s[4], r_p[4];
    if ((tid & 63) == 0) r_s[tid >> 6] = w;
    if (do_price) {
        for (int off = 32; off > 0; off >>= 1) pp += __shfl_down(pp, off, 64);
        if ((tid & 63) == 0) r_p[tid >> 6] = pp;
    }
    __syncthreads();
    if (tid == 0) {
        rank_part[blockIdx.x] = r_s[0] + r_s[1] + r_s[2] + r_s[3];
        if (do_price) price_part[ib] = r_p[0] + r_p[1] + r_p[2] + r_p[3];
    }
}

__global__ __launch_bounds__(256)
void finalize_kernel(const float* __restrict__ rank_part,
                     const float* __restrict__ price_part,
                     float* __restrict__ out)
{
    double s = 0.0, p = 0.0;
    for (int t = threadIdx.x; t < NBLOCKS; t += 256) s += (double)rank_part[t];
    if (threadIdx.x < NTI) p = (double)price_part[threadIdx.x];
    for (int off = 32; off > 0; off >>= 1) {
        s += __shfl_down(s, off, 64);
        p += __shfl_down(p, off, 64);
    }
    __shared__ double rs[4], rp[4];
    const int w = threadIdx.x >> 6;
    if ((threadIdx.x & 63) == 0) { rs[w] = s; rp[w] = p; }
    __syncthreads();
    if (threadIdx.x == 0) {
        const double S = rs[0] + rs[1] + rs[2] + rs[3];
        const double P = rp[0] + rp[1] + rp[2] + rp[3];
        const double rank = (S - (double)NN * (double)MARGIN)
                          / ((double)NN * (double)(NN - 1));
        out[0] = (float)(0.5 * (P / (double)NN) + 0.5 * rank);
    }
}

extern "C" void kernel_launch(void* const* d_in, const int* in_sizes, int n_in,
                              void* d_out, int out_size, void* d_ws, size_t ws_size,
                              hipStream_t stream)
{
    const float* pred = (const float*)d_in[0];
    const float* act  = (const float*)d_in[1];
    const float* prev = (const float*)d_in[2];

    char* w = (char*)d_ws;
    float* rank_part  = (float*)w;             // 1152 * 4 B
    float* price_part = (float*)(w + 8192);    // 8 * 4 B

    pair_kernel<<<NBLOCKS, BT, 0, stream>>>(pred, act, prev, rank_part, price_part);
    finalize_kernel<<<1, 256, 0, stream>>>(rank_part, price_part, (float*)d_out);
}